// Round 3
// baseline (3279.519 us; speedup 1.0000x reference)
//
#include <hip/hip_runtime.h>
#include <cstdint>
#include <cstddef>

// BottomUpNet: N=8192 rows independent; K=16 sequential steps.
// R14: occupancy fix. R13 post-mortem: per-CU matrix-pipe work is 13.6us
// of a 47.7us dispatch (29% = MfmaUtil); the stall is barrier drains with
// only 2 resident blocks/CU (grid 512/256CU, Occupancy 18%). The 3.34M
// SQ_LDS_BANK_CONFLICT is bit-identical across R11/R13's different
// layouts = inherent b128 8-cycle floor, NOT a real conflict — ignore it.
// Change: 128x64 tiles -> grid (64,16) = 1024 blocks = 4 blocks/CU.
// LDS 32KB (split) / 24KB (h). Waves 2x2, each owns 64x32 (acc[2]).
// B total staging unchanged; A restaged 2x (extra ~140MB L2 @ ~4TB/s, ok).
// XCD A-pinning kept: 64%8==0 -> XCD=bx%8, bx indexes M rows.
// 2-phase BK=32 dbuf kept (barrier cost now hidden by 3 other blocks).
// Accumulation order per output element unchanged: absmax must stay
// 1.192093e-07 — revert if it moves.

typedef _Float16 f16x8 __attribute__((ext_vector_type(8)));
typedef float f32x16 __attribute__((ext_vector_type(16)));

__device__ __forceinline__ void gload16(const void* g, void* l) {
  // async global->LDS, 16B/lane, LDS dest = wave-uniform base + lane*16
  __builtin_amdgcn_global_load_lds(
      (__attribute__((address_space(1))) void*)const_cast<void*>(g),
      (__attribute__((address_space(3))) void*)l,
      16, 0, 0);
}

// ---- m-GEMM: C = relu(A@B^T + bias); A fp16 hi; B hi/lo fp16 (2 MFMAs);
// C stored fp16 hi. Tile 128x64, BK=32 double-buffered, 256 thr (4 waves).
__global__ __launch_bounds__(256, 4)
void gemm_split_kernel(const _Float16* __restrict__ AH0, int ldA0,
                       const _Float16* __restrict__ AH1, int ldA1,
                       int kcut, int Ktot,
                       const _Float16* __restrict__ BH, const _Float16* __restrict__ BL,
                       const float* __restrict__ bias,
                       _Float16* __restrict__ CH, int ldC)
{
  __shared__ _Float16 sAh[2][128 * 32];
  __shared__ _Float16 sBh[2][64 * 32];
  __shared__ _Float16 sBl[2][64 * 32];

  const int lane = threadIdx.x & 63;
  const int wave = threadIdx.x >> 6;
  const int wm = (wave >> 1) * 64, wn = (wave & 1) * 32;
  const int mBase = blockIdx.x * 128, nBase = blockIdx.y * 64;

  // staging (paired-row layout): chunk = 16 logical rows = 8 phys 128-B rows.
  // lane l -> phys byte l*16: logical row 2*(l>>3)+((l>>2)&1),
  // stored seg p = l&3 holds global seg g = p ^ ((l>>3)&3)
  const int lr  = 2 * (lane >> 3) + ((lane >> 2) & 1);     // logical row 0..15
  const int lcs = (((lane & 3) ^ ((lane >> 3) & 3)) * 8);  // src k-seg (halves)
  // chunk assignment: A chunks 2w,2w+1 (of 8); B chunk w (of 4)
  const int cA0 = wave * 2, cA1 = wave * 2 + 1;
  const int rA0 = cA0 * 16 + lr, rA1 = cA1 * 16 + lr;
  const int rB  = wave * 16 + lr;

  // fragment read coords: logical row r -> (r>>1)*64 + (r&1)*32 + (g^((r>>1)&3))*8
  const int l31 = lane & 31, l5 = lane >> 5;
  const int rowoff = (l31 >> 1) * 64 + (l31 & 1) * 32;     // lane-const part
  const int fswz = (l31 >> 1) & 3;

  const _Float16* aP00 = AH0 + (size_t)(mBase + rA0) * ldA0 + lcs;
  const _Float16* aP01 = AH0 + (size_t)(mBase + rA1) * ldA0 + lcs;
  const _Float16* aP10 = AH1 + (size_t)(mBase + rA0) * ldA1 + lcs;
  const _Float16* aP11 = AH1 + (size_t)(mBase + rA1) * ldA1 + lcs;
  const _Float16* bHp  = BH + (size_t)(nBase + rB) * Ktot + lcs;
  const _Float16* bLp  = BL + (size_t)(nBase + rB) * Ktot + lcs;

  f32x16 acc[2];
#pragma unroll
  for (int i = 0; i < 2; ++i) acc[i] = (f32x16)0.0f;

  auto STAGE = [&](int b, int kt) {
    const _Float16 *a0, *a1;
    if (kt < kcut) { a0 = aP00 + kt; a1 = aP01 + kt; }
    else           { a0 = aP10 + (kt - kcut); a1 = aP11 + (kt - kcut); }
    gload16(a0,       &sAh[b][cA0 * 512]);
    gload16(a1,       &sAh[b][cA1 * 512]);
    gload16(bHp + kt, &sBh[b][wave * 512]);
    gload16(bLp + kt, &sBl[b][wave * 512]);
  };

  auto COMPUTE = [&](int b) {
#pragma unroll
    for (int kh = 0; kh < 2; ++kh) {            // two K=16 MFMAs per BK=32
      const int g = kh * 2 + l5;
      const int ko = ((g ^ fswz) * 8);
      f16x8 ah[2], bh, bl;
#pragma unroll
      for (int i = 0; i < 2; ++i)
        ah[i] = *(const f16x8*)&sAh[b][(wm + i * 32) * 32 + rowoff + ko];
      {
        const int off = wn * 32 + rowoff + ko;
        bh = *(const f16x8*)&sBh[b][off];
        bl = *(const f16x8*)&sBl[b][off];
      }
#pragma unroll
      for (int i = 0; i < 2; ++i) {
        acc[i] = __builtin_amdgcn_mfma_f32_32x32x16_f16(ah[i], bl, acc[i], 0, 0, 0);
        acc[i] = __builtin_amdgcn_mfma_f32_32x32x16_f16(ah[i], bh, acc[i], 0, 0, 0);
      }
    }
  };

  const int NT = Ktot >> 5;
  STAGE(0, 0);
  __syncthreads();                 // buf0 ready
  int cur = 0;
  for (int t = 1; t < NT; ++t) {
    STAGE(cur ^ 1, t * 32);        // prefetch flies under compute
    COMPUTE(cur);
    __syncthreads();               // drains prefetch + all reads of cur
    cur ^= 1;
  }
  COMPUTE(cur);

  const float bv = bias[nBase + wn + l31];
#pragma unroll
  for (int i = 0; i < 2; ++i)
#pragma unroll
    for (int r = 0; r < 16; ++r) {
      const int row = mBase + wm + i * 32 + (r & 3) + 8 * (r >> 2) + 4 * l5;
      const int col = nBase + wn + l31;
      float v = fmaxf(acc[i][r] + bv, 0.0f);
      CH[(size_t)row * ldC + col] = (_Float16)v;
    }
}

// ---- fp16 GEMM (hi-only, 1 MFMA): C = relu(A@B^T + bias) fp16 out,
// or fused-pred mode (sacc != null): sacc[row] += sum_col relu(.)*w3[col]
__global__ __launch_bounds__(256, 4)
void gemm_h_kernel(const _Float16* __restrict__ A0, int ldA0,
                   const _Float16* __restrict__ A1, int ldA1,
                   int kcut, int Ktot,
                   const _Float16* __restrict__ B,
                   const float* __restrict__ bias,
                   _Float16* __restrict__ C, int ldC,
                   const float* __restrict__ w3, float* __restrict__ sacc)
{
  __shared__ _Float16 sAh[2][128 * 32];
  __shared__ _Float16 sBh[2][64 * 32];

  const int lane = threadIdx.x & 63;
  const int wave = threadIdx.x >> 6;
  const int wm = (wave >> 1) * 64, wn = (wave & 1) * 32;
  const int mBase = blockIdx.x * 128, nBase = blockIdx.y * 64;

  const int lr  = 2 * (lane >> 3) + ((lane >> 2) & 1);
  const int lcs = (((lane & 3) ^ ((lane >> 3) & 3)) * 8);
  const int cA0 = wave * 2, cA1 = wave * 2 + 1;
  const int rA0 = cA0 * 16 + lr, rA1 = cA1 * 16 + lr;
  const int rB  = wave * 16 + lr;

  const int l31 = lane & 31, l5 = lane >> 5;
  const int rowoff = (l31 >> 1) * 64 + (l31 & 1) * 32;
  const int fswz = (l31 >> 1) & 3;

  const _Float16* aP00 = A0 + (size_t)(mBase + rA0) * ldA0 + lcs;
  const _Float16* aP01 = A0 + (size_t)(mBase + rA1) * ldA0 + lcs;
  const _Float16* aP10 = A1 + (size_t)(mBase + rA0) * ldA1 + lcs;
  const _Float16* aP11 = A1 + (size_t)(mBase + rA1) * ldA1 + lcs;
  const _Float16* bHp  = B + (size_t)(nBase + rB) * Ktot + lcs;

  f32x16 acc[2];
#pragma unroll
  for (int i = 0; i < 2; ++i) acc[i] = (f32x16)0.0f;

  auto STAGE = [&](int b, int kt) {
    const _Float16 *a0, *a1;
    if (kt < kcut) { a0 = aP00 + kt; a1 = aP01 + kt; }
    else           { a0 = aP10 + (kt - kcut); a1 = aP11 + (kt - kcut); }
    gload16(a0,       &sAh[b][cA0 * 512]);
    gload16(a1,       &sAh[b][cA1 * 512]);
    gload16(bHp + kt, &sBh[b][wave * 512]);
  };

  auto COMPUTE = [&](int b) {
#pragma unroll
    for (int kh = 0; kh < 2; ++kh) {
      const int g = kh * 2 + l5;
      const int ko = ((g ^ fswz) * 8);
      f16x8 ah[2], bh;
#pragma unroll
      for (int i = 0; i < 2; ++i)
        ah[i] = *(const f16x8*)&sAh[b][(wm + i * 32) * 32 + rowoff + ko];
      bh = *(const f16x8*)&sBh[b][wn * 32 + rowoff + ko];
#pragma unroll
      for (int i = 0; i < 2; ++i)
        acc[i] = __builtin_amdgcn_mfma_f32_32x32x16_f16(ah[i], bh, acc[i], 0, 0, 0);
    }
  };

  const int NT = Ktot >> 5;
  STAGE(0, 0);
  __syncthreads();
  int cur = 0;
  for (int t = 1; t < NT; ++t) {
    STAGE(cur ^ 1, t * 32);
    COMPUTE(cur);
    __syncthreads();
    cur ^= 1;
  }
  COMPUTE(cur);

  const int col = nBase + wn + l31;
  const float bv = bias[col];
  const float w3v = sacc ? w3[col] : 0.0f;

  if (sacc) {
    // fused pred partial: one value per C/D row, reduced over the 32 col-lanes
#pragma unroll
    for (int i = 0; i < 2; ++i)
#pragma unroll
      for (int r = 0; r < 16; ++r) {
        float pr = fmaxf(acc[i][r] + bv, 0.0f) * w3v;
        pr += __shfl_xor(pr, 1);
        pr += __shfl_xor(pr, 2);
        pr += __shfl_xor(pr, 4);
        pr += __shfl_xor(pr, 8);
        pr += __shfl_xor(pr, 16);
        if (l31 == 0)
          atomicAdd(&sacc[mBase + wm + i * 32 + (r & 3) + 8 * (r >> 2) + 4 * l5], pr);
      }
  } else {
#pragma unroll
    for (int i = 0; i < 2; ++i)
#pragma unroll
      for (int r = 0; r < 16; ++r) {
        const int row = mBase + wm + i * 32 + (r & 3) + 8 * (r >> 2) + 4 * l5;
        float v = fmaxf(acc[i][r] + bv, 0.0f);
        C[(size_t)row * ldC + col] = (_Float16)v;
      }
  }
}

// W (K x N fp32, row-major) -> out (N x K fp16 hi[/lo]), i.e. transposed
__global__ void wconv_kernel(const float* __restrict__ W, int K, int N,
                             _Float16* __restrict__ oH, _Float16* __restrict__ oL) {
  int idx = blockIdx.x * 256 + threadIdx.x;   // idx = n*K + k (output-coalesced)
  if (idx >= K * N) return;
  int n = idx / K, k = idx - n * K;
  float v = W[(size_t)k * N + n];
  _Float16 h = (_Float16)v;
  oH[idx] = h;
  if (oL) oL[idx] = (_Float16)(v - (float)h);
}

__global__ void init_summary_kernel(const float* __restrict__ agg,
                                    _Float16* __restrict__ sH,
                                    float* __restrict__ sacc) {
  int idx = blockIdx.x * 256 + threadIdx.x;   // 8192*1024
  sH[idx] = (_Float16)agg[idx & 1023];
  if (idx < 8192) sacc[idx] = 0.0f;
}

// towers [n][k][f] fp32 -> towAll [k][n][f] fp16 hi (all 16 slices)
__global__ void tow_conv_all_kernel(const float* __restrict__ towers,
                                    _Float16* __restrict__ oH) {
  size_t idx = (size_t)blockIdx.x * 256 + threadIdx.x;  // (k*8192+n)*64+f
  int f = idx & 63;
  int n = (int)((idx >> 6) & 8191);
  int k = (int)(idx >> 19);
  oH[idx] = (_Float16)towers[((size_t)n * 16 + k) * 64 + f];
}

// pred = sigmoid(sacc + Ob3); out *= pred; re-zero sacc for next step
__global__ void pred_final_kernel(float* __restrict__ sacc, const float* __restrict__ b3,
                                  float* __restrict__ out, int step) {
  int row = blockIdx.x * 256 + threadIdx.x;   // 8192
  float p = 1.0f / (1.0f + expf(-(sacc[row] + b3[0])));
  out[row] = (step == 0) ? p : out[row] * p;
  sacc[row] = 0.0f;
}

extern "C" void kernel_launch(void* const* d_in, const int* in_sizes, int n_in,
                              void* d_out, int out_size, void* d_ws, size_t ws_size,
                              hipStream_t stream) {
  const float* towers = (const float*)d_in[0];
  const float* agg    = (const float*)d_in[1];
  const float* MW1 = (const float*)d_in[2];
  const float* Mb1 = (const float*)d_in[3];
  const float* MW2 = (const float*)d_in[4];
  const float* Mb2 = (const float*)d_in[5];
  const float* MW3 = (const float*)d_in[6];
  const float* Mb3 = (const float*)d_in[7];
  const float* OW1 = (const float*)d_in[8];
  const float* Ob1 = (const float*)d_in[9];
  const float* OW2 = (const float*)d_in[10];
  const float* Ob2 = (const float*)d_in[11];
  const float* OW3 = (const float*)d_in[12];
  const float* Ob3 = (const float*)d_in[13];
  float* out = (float*)d_out;

  // ws layout (~110 MiB)
  _Float16* p = (_Float16*)d_ws;
  _Float16* MW1tH = p; p += (size_t)1024 * 1088;
  _Float16* MW1tL = p; p += (size_t)1024 * 1088;
  _Float16* OW1tH = p; p += (size_t)1024 * 1088;
  _Float16* MW2tH = p; p += (size_t)1024 * 1024;
  _Float16* MW2tL = p; p += (size_t)1024 * 1024;
  _Float16* OW2tH = p; p += (size_t)1024 * 1024;
  _Float16* MW3tH = p; p += (size_t)1024 * 1024;
  _Float16* MW3tL = p; p += (size_t)1024 * 1024;
  _Float16* sumH  = p; p += (size_t)8192 * 1024;
  _Float16* m1H   = p; p += (size_t)8192 * 1024;
  _Float16* h1    = p; p += (size_t)8192 * 1024;
  _Float16* m2H   = p; p += (size_t)8192 * 1024;
  _Float16* towAllH = p; p += (size_t)16 * 8192 * 64;
  float* sacc = (float*)p;

  // per-call setup: transpose+split weights, convert towers, init summary
  {
    int tot = 1088 * 1024;
    wconv_kernel<<<dim3((tot + 255) / 256), dim3(256), 0, stream>>>(MW1, 1088, 1024, MW1tH, MW1tL);
    wconv_kernel<<<dim3((tot + 255) / 256), dim3(256), 0, stream>>>(OW1, 1088, 1024, OW1tH, nullptr);
    tot = 1024 * 1024;
    wconv_kernel<<<dim3((tot + 255) / 256), dim3(256), 0, stream>>>(MW2, 1024, 1024, MW2tH, MW2tL);
    wconv_kernel<<<dim3((tot + 255) / 256), dim3(256), 0, stream>>>(OW2, 1024, 1024, OW2tH, nullptr);
    wconv_kernel<<<dim3((tot + 255) / 256), dim3(256), 0, stream>>>(MW3, 1024, 1024, MW3tH, MW3tL);
    init_summary_kernel<<<dim3(32768), dim3(256), 0, stream>>>(agg, sumH, sacc);
    tow_conv_all_kernel<<<dim3(32768), dim3(256), 0, stream>>>(towers, towAllH);
  }

  const dim3 G(64, 16), B256(256);  // 128x64 tiles over 8192x1024 -> 1024 blocks
  for (int k = 0; k < 16; ++k) {
    const _Float16* towH = towAllH + (size_t)k * 8192 * 64;

    // K1m: x=[sum|tow] @ MW1^T -> m1 (2-MFMA: weight-lo kept)
    gemm_split_kernel<<<G, B256, 0, stream>>>(sumH, 1024, towH, 64,
                                              1024, 1088, MW1tH, MW1tL, Mb1, m1H, 1024);
    // K1h: x=[sum|tow] @ OW1^T -> h1 (fp16)
    gemm_h_kernel<<<G, B256, 0, stream>>>(sumH, 1024, towH, 64, 1024, 1088,
                                          OW1tH, Ob1, h1, 1024, nullptr, nullptr);
    // K2m: m1 @ MW2^T -> m2 (2-MFMA)
    gemm_split_kernel<<<G, B256, 0, stream>>>(m1H, 1024, m1H, 1024,
                                              1024, 1024, MW2tH, MW2tL, Mb2, m2H, 1024);
    // K2h: h1 @ OW2^T -> fused relu+dot(OW3) into sacc (fp16)
    gemm_h_kernel<<<G, B256, 0, stream>>>(h1, 1024, h1, 1024, 1024, 1024,
                                          OW2tH, Ob2, nullptr, 1024, OW3, sacc);
    // K3: m2 @ MW3^T -> summary (2-MFMA; in-place: K1m/K1h already consumed it)
    gemm_split_kernel<<<G, B256, 0, stream>>>(m2H, 1024, m2H, 1024,
                                              1024, 1024, MW3tH, MW3tL, Mb3, sumH, 1024);
    // pred + product accumulate + re-zero sacc
    pred_final_kernel<<<dim3(32), B256, 0, stream>>>(sacc, Ob3, out, k);
  }
}

// Round 4
// 3077.419 us; speedup vs baseline: 1.0657x; 1.0657x over previous
//
#include <hip/hip_runtime.h>
#include <cstdint>
#include <cstddef>

// BottomUpNet: N=8192 rows independent; K=16 sequential steps.
// R15: T4 counted-vmcnt pipeline. R14 falsified the occupancy theory
// (Occupancy 18->34%, MfmaUtil DOWN 31->29, time flat): the stall is the
// __syncthreads vmcnt(0) drain itself — every block stalls synchronously
// on its own just-issued prefetch. Fix per guide T3/T4 (m218: counted-vs-
// drain0 = +38-73%): 3-buffer LDS, raw s_barrier, s_waitcnt vmcnt(6)
// (split; 6 loads/tile in flight beyond current) / vmcnt(4) (h kernel),
// never 0 in the main loop. STAGE(t+2) placed AFTER the barrier (hazard:
// it overwrites buf (t-1)%3; barrier at iter t is after all waves'
// COMPUTE(t-1)). Fences: "memory"-clobber waitcnt asm + sched_barrier(0)
// after s_barrier (rule #18: block ds_read hoist/sink across barrier).
// Geometry reverted to R13: 128x128 tiles, G(64,8), BK=32, paired-row
// swizzled LDS layout (verified), natural XCD A-pinning.
// LDS: split 3x24=72KB (2 blk/CU), h 3x16=48KB (3 blk/CU).
// MFMA order per output unchanged: absmax must stay 1.192093e-07.

typedef _Float16 f16x8 __attribute__((ext_vector_type(8)));
typedef float f32x16 __attribute__((ext_vector_type(16)));

__device__ __forceinline__ void gload16(const void* g, void* l) {
  // async global->LDS, 16B/lane, LDS dest = wave-uniform base + lane*16
  __builtin_amdgcn_global_load_lds(
      (__attribute__((address_space(1))) void*)const_cast<void*>(g),
      (__attribute__((address_space(3))) void*)l,
      16, 0, 0);
}

// ---- m-GEMM: C = relu(A@B^T + bias); A fp16 hi; B hi/lo fp16 (2 MFMAs);
// C stored fp16 hi. Tile 128x128, BK=32, 3-buffer counted-vmcnt pipeline.
__global__ __launch_bounds__(256, 2)
void gemm_split_kernel(const _Float16* __restrict__ AH0, int ldA0,
                       const _Float16* __restrict__ AH1, int ldA1,
                       int kcut, int Ktot,
                       const _Float16* __restrict__ BH, const _Float16* __restrict__ BL,
                       const float* __restrict__ bias,
                       _Float16* __restrict__ CH, int ldC)
{
  __shared__ _Float16 sAh[3][128 * 32];
  __shared__ _Float16 sBh[3][128 * 32];
  __shared__ _Float16 sBl[3][128 * 32];

  const int lane = threadIdx.x & 63;
  const int wave = threadIdx.x >> 6;
  const int wm = (wave >> 1) * 64, wn = (wave & 1) * 64;
  const int mBase = blockIdx.x * 128, nBase = blockIdx.y * 128;

  // staging (paired-row layout): chunk = 16 logical rows = 8 phys 128-B rows.
  // lane l -> phys byte l*16: logical row 2*(l>>3)+((l>>2)&1),
  // stored seg p = l&3 holds global seg g = p ^ ((l>>3)&3)
  const int lr  = 2 * (lane >> 3) + ((lane >> 2) & 1);     // logical row 0..15
  const int lcs = (((lane & 3) ^ ((lane >> 3) & 3)) * 8);  // src k-seg (halves)
  const int c0 = wave * 2, c1 = wave * 2 + 1;              // chunks per wave
  const int r0 = c0 * 16 + lr, r1 = c1 * 16 + lr;

  // fragment read coords: row r -> (r>>1)*64 + (r&1)*32 + (g^((r>>1)&3))*8
  const int l31 = lane & 31, l5 = lane >> 5;
  const int rowoff = (l31 >> 1) * 64 + (l31 & 1) * 32;     // lane-const part
  const int fswz = (l31 >> 1) & 3;

  const _Float16* aP00 = AH0 + (size_t)(mBase + r0) * ldA0 + lcs;
  const _Float16* aP01 = AH0 + (size_t)(mBase + r1) * ldA0 + lcs;
  const _Float16* aP10 = AH1 + (size_t)(mBase + r0) * ldA1 + lcs;
  const _Float16* aP11 = AH1 + (size_t)(mBase + r1) * ldA1 + lcs;
  const _Float16* bHp0 = BH + (size_t)(nBase + r0) * Ktot + lcs;
  const _Float16* bHp1 = BH + (size_t)(nBase + r1) * Ktot + lcs;
  const _Float16* bLp0 = BL + (size_t)(nBase + r0) * Ktot + lcs;
  const _Float16* bLp1 = BL + (size_t)(nBase + r1) * Ktot + lcs;

  f32x16 acc[2][2];
#pragma unroll
  for (int i = 0; i < 2; ++i)
#pragma unroll
    for (int j = 0; j < 2; ++j)
      acc[i][j] = (f32x16)0.0f;

  auto STAGE = [&](int b, int kt) {
    const _Float16 *a0, *a1;
    if (kt < kcut) { a0 = aP00 + kt; a1 = aP01 + kt; }
    else           { a0 = aP10 + (kt - kcut); a1 = aP11 + (kt - kcut); }
    gload16(a0,        &sAh[b][c0 * 512]);
    gload16(a1,        &sAh[b][c1 * 512]);
    gload16(bHp0 + kt, &sBh[b][c0 * 512]);
    gload16(bHp1 + kt, &sBh[b][c1 * 512]);
    gload16(bLp0 + kt, &sBl[b][c0 * 512]);
    gload16(bLp1 + kt, &sBl[b][c1 * 512]);
  };

  auto COMPUTE = [&](int b) {
#pragma unroll
    for (int kh = 0; kh < 2; ++kh) {            // two K=16 MFMAs per BK=32
      const int g = kh * 2 + l5;
      const int ko = ((g ^ fswz) * 8);
      f16x8 ah[2], bh[2], bl[2];
#pragma unroll
      for (int i = 0; i < 2; ++i)
        ah[i] = *(const f16x8*)&sAh[b][(wm + i * 32) * 32 + rowoff + ko];
#pragma unroll
      for (int j = 0; j < 2; ++j) {
        const int off = (wn + j * 32) * 32 + rowoff + ko;
        bh[j] = *(const f16x8*)&sBh[b][off];
        bl[j] = *(const f16x8*)&sBl[b][off];
      }
#pragma unroll
      for (int i = 0; i < 2; ++i)
#pragma unroll
        for (int j = 0; j < 2; ++j) {
          acc[i][j] = __builtin_amdgcn_mfma_f32_32x32x16_f16(ah[i], bl[j], acc[i][j], 0, 0, 0);
          acc[i][j] = __builtin_amdgcn_mfma_f32_32x32x16_f16(ah[i], bh[j], acc[i][j], 0, 0, 0);
        }
    }
  };

  const int NT = Ktot >> 5;
  STAGE(0, 0);
  if (NT > 1) STAGE(1, 32);
  for (int t = 0; t < NT; ++t) {
    if (t + 1 < NT) { asm volatile("s_waitcnt vmcnt(6)" ::: "memory"); }
    else            { asm volatile("s_waitcnt vmcnt(0)" ::: "memory"); }
    __builtin_amdgcn_s_barrier();
    __builtin_amdgcn_sched_barrier(0);
    if (t + 2 < NT) STAGE((t + 2) % 3, (t + 2) * 32);
    COMPUTE(t % 3);
  }

  float bv[2];
#pragma unroll
  for (int j = 0; j < 2; ++j) bv[j] = bias[nBase + wn + j * 32 + l31];
#pragma unroll
  for (int i = 0; i < 2; ++i)
#pragma unroll
    for (int j = 0; j < 2; ++j)
#pragma unroll
      for (int r = 0; r < 16; ++r) {
        const int row = mBase + wm + i * 32 + (r & 3) + 8 * (r >> 2) + 4 * l5;
        const int col = nBase + wn + j * 32 + l31;
        float v = fmaxf(acc[i][j][r] + bv[j], 0.0f);
        CH[(size_t)row * ldC + col] = (_Float16)v;
      }
}

// ---- fp16 GEMM (hi-only, 1 MFMA): C = relu(A@B^T + bias) fp16 out,
// or fused-pred mode (sacc != null): sacc[row] += sum_col relu(.)*w3[col]
__global__ __launch_bounds__(256, 3)
void gemm_h_kernel(const _Float16* __restrict__ A0, int ldA0,
                   const _Float16* __restrict__ A1, int ldA1,
                   int kcut, int Ktot,
                   const _Float16* __restrict__ B,
                   const float* __restrict__ bias,
                   _Float16* __restrict__ C, int ldC,
                   const float* __restrict__ w3, float* __restrict__ sacc)
{
  __shared__ _Float16 sAh[3][128 * 32];
  __shared__ _Float16 sBh[3][128 * 32];

  const int lane = threadIdx.x & 63;
  const int wave = threadIdx.x >> 6;
  const int wm = (wave >> 1) * 64, wn = (wave & 1) * 64;
  const int mBase = blockIdx.x * 128, nBase = blockIdx.y * 128;

  const int lr  = 2 * (lane >> 3) + ((lane >> 2) & 1);
  const int lcs = (((lane & 3) ^ ((lane >> 3) & 3)) * 8);
  const int c0 = wave * 2, c1 = wave * 2 + 1;
  const int r0 = c0 * 16 + lr, r1 = c1 * 16 + lr;

  const int l31 = lane & 31, l5 = lane >> 5;
  const int rowoff = (l31 >> 1) * 64 + (l31 & 1) * 32;
  const int fswz = (l31 >> 1) & 3;

  const _Float16* aP00 = A0 + (size_t)(mBase + r0) * ldA0 + lcs;
  const _Float16* aP01 = A0 + (size_t)(mBase + r1) * ldA0 + lcs;
  const _Float16* aP10 = A1 + (size_t)(mBase + r0) * ldA1 + lcs;
  const _Float16* aP11 = A1 + (size_t)(mBase + r1) * ldA1 + lcs;
  const _Float16* bHp0 = B + (size_t)(nBase + r0) * Ktot + lcs;
  const _Float16* bHp1 = B + (size_t)(nBase + r1) * Ktot + lcs;

  f32x16 acc[2][2];
#pragma unroll
  for (int i = 0; i < 2; ++i)
#pragma unroll
    for (int j = 0; j < 2; ++j)
      acc[i][j] = (f32x16)0.0f;

  auto STAGE = [&](int b, int kt) {
    const _Float16 *a0, *a1;
    if (kt < kcut) { a0 = aP00 + kt; a1 = aP01 + kt; }
    else           { a0 = aP10 + (kt - kcut); a1 = aP11 + (kt - kcut); }
    gload16(a0,        &sAh[b][c0 * 512]);
    gload16(a1,        &sAh[b][c1 * 512]);
    gload16(bHp0 + kt, &sBh[b][c0 * 512]);
    gload16(bHp1 + kt, &sBh[b][c1 * 512]);
  };

  auto COMPUTE = [&](int b) {
#pragma unroll
    for (int kh = 0; kh < 2; ++kh) {
      const int g = kh * 2 + l5;
      const int ko = ((g ^ fswz) * 8);
      f16x8 ah[2], bh[2];
#pragma unroll
      for (int i = 0; i < 2; ++i)
        ah[i] = *(const f16x8*)&sAh[b][(wm + i * 32) * 32 + rowoff + ko];
#pragma unroll
      for (int j = 0; j < 2; ++j)
        bh[j] = *(const f16x8*)&sBh[b][(wn + j * 32) * 32 + rowoff + ko];
#pragma unroll
      for (int i = 0; i < 2; ++i)
#pragma unroll
        for (int j = 0; j < 2; ++j)
          acc[i][j] = __builtin_amdgcn_mfma_f32_32x32x16_f16(ah[i], bh[j], acc[i][j], 0, 0, 0);
    }
  };

  const int NT = Ktot >> 5;
  STAGE(0, 0);
  if (NT > 1) STAGE(1, 32);
  for (int t = 0; t < NT; ++t) {
    if (t + 1 < NT) { asm volatile("s_waitcnt vmcnt(4)" ::: "memory"); }
    else            { asm volatile("s_waitcnt vmcnt(0)" ::: "memory"); }
    __builtin_amdgcn_s_barrier();
    __builtin_amdgcn_sched_barrier(0);
    if (t + 2 < NT) STAGE((t + 2) % 3, (t + 2) * 32);
    COMPUTE(t % 3);
  }

  float bv[2], w3v[2];
#pragma unroll
  for (int j = 0; j < 2; ++j) {
    const int col = nBase + wn + j * 32 + l31;
    bv[j] = bias[col];
    w3v[j] = sacc ? w3[col] : 0.0f;
  }

  if (sacc) {
    // fused pred partial: one value per C/D row, reduced over the 32 col-lanes
#pragma unroll
    for (int i = 0; i < 2; ++i)
#pragma unroll
      for (int r = 0; r < 16; ++r) {
        float pr = 0.0f;
#pragma unroll
        for (int j = 0; j < 2; ++j)
          pr += fmaxf(acc[i][j][r] + bv[j], 0.0f) * w3v[j];
        pr += __shfl_xor(pr, 1);
        pr += __shfl_xor(pr, 2);
        pr += __shfl_xor(pr, 4);
        pr += __shfl_xor(pr, 8);
        pr += __shfl_xor(pr, 16);
        if (l31 == 0)
          atomicAdd(&sacc[mBase + wm + i * 32 + (r & 3) + 8 * (r >> 2) + 4 * l5], pr);
      }
  } else {
#pragma unroll
    for (int i = 0; i < 2; ++i)
#pragma unroll
      for (int j = 0; j < 2; ++j)
#pragma unroll
        for (int r = 0; r < 16; ++r) {
          const int row = mBase + wm + i * 32 + (r & 3) + 8 * (r >> 2) + 4 * l5;
          const int col = nBase + wn + j * 32 + l31;
          float v = fmaxf(acc[i][j][r] + bv[j], 0.0f);
          C[(size_t)row * ldC + col] = (_Float16)v;
        }
  }
}

// W (K x N fp32, row-major) -> out (N x K fp16 hi[/lo]), i.e. transposed
__global__ void wconv_kernel(const float* __restrict__ W, int K, int N,
                             _Float16* __restrict__ oH, _Float16* __restrict__ oL) {
  int idx = blockIdx.x * 256 + threadIdx.x;   // idx = n*K + k (output-coalesced)
  if (idx >= K * N) return;
  int n = idx / K, k = idx - n * K;
  float v = W[(size_t)k * N + n];
  _Float16 h = (_Float16)v;
  oH[idx] = h;
  if (oL) oL[idx] = (_Float16)(v - (float)h);
}

__global__ void init_summary_kernel(const float* __restrict__ agg,
                                    _Float16* __restrict__ sH,
                                    float* __restrict__ sacc) {
  int idx = blockIdx.x * 256 + threadIdx.x;   // 8192*1024
  sH[idx] = (_Float16)agg[idx & 1023];
  if (idx < 8192) sacc[idx] = 0.0f;
}

// towers [n][k][f] fp32 -> towAll [k][n][f] fp16 hi (all 16 slices)
__global__ void tow_conv_all_kernel(const float* __restrict__ towers,
                                    _Float16* __restrict__ oH) {
  size_t idx = (size_t)blockIdx.x * 256 + threadIdx.x;  // (k*8192+n)*64+f
  int f = idx & 63;
  int n = (int)((idx >> 6) & 8191);
  int k = (int)(idx >> 19);
  oH[idx] = (_Float16)towers[((size_t)n * 16 + k) * 64 + f];
}

// pred = sigmoid(sacc + Ob3); out *= pred; re-zero sacc for next step
__global__ void pred_final_kernel(float* __restrict__ sacc, const float* __restrict__ b3,
                                  float* __restrict__ out, int step) {
  int row = blockIdx.x * 256 + threadIdx.x;   // 8192
  float p = 1.0f / (1.0f + expf(-(sacc[row] + b3[0])));
  out[row] = (step == 0) ? p : out[row] * p;
  sacc[row] = 0.0f;
}

extern "C" void kernel_launch(void* const* d_in, const int* in_sizes, int n_in,
                              void* d_out, int out_size, void* d_ws, size_t ws_size,
                              hipStream_t stream) {
  const float* towers = (const float*)d_in[0];
  const float* agg    = (const float*)d_in[1];
  const float* MW1 = (const float*)d_in[2];
  const float* Mb1 = (const float*)d_in[3];
  const float* MW2 = (const float*)d_in[4];
  const float* Mb2 = (const float*)d_in[5];
  const float* MW3 = (const float*)d_in[6];
  const float* Mb3 = (const float*)d_in[7];
  const float* OW1 = (const float*)d_in[8];
  const float* Ob1 = (const float*)d_in[9];
  const float* OW2 = (const float*)d_in[10];
  const float* Ob2 = (const float*)d_in[11];
  const float* OW3 = (const float*)d_in[12];
  const float* Ob3 = (const float*)d_in[13];
  float* out = (float*)d_out;

  // ws layout (~110 MiB)
  _Float16* p = (_Float16*)d_ws;
  _Float16* MW1tH = p; p += (size_t)1024 * 1088;
  _Float16* MW1tL = p; p += (size_t)1024 * 1088;
  _Float16* OW1tH = p; p += (size_t)1024 * 1088;
  _Float16* MW2tH = p; p += (size_t)1024 * 1024;
  _Float16* MW2tL = p; p += (size_t)1024 * 1024;
  _Float16* OW2tH = p; p += (size_t)1024 * 1024;
  _Float16* MW3tH = p; p += (size_t)1024 * 1024;
  _Float16* MW3tL = p; p += (size_t)1024 * 1024;
  _Float16* sumH  = p; p += (size_t)8192 * 1024;
  _Float16* m1H   = p; p += (size_t)8192 * 1024;
  _Float16* h1    = p; p += (size_t)8192 * 1024;
  _Float16* m2H   = p; p += (size_t)8192 * 1024;
  _Float16* towAllH = p; p += (size_t)16 * 8192 * 64;
  float* sacc = (float*)p;

  // per-call setup: transpose+split weights, convert towers, init summary
  {
    int tot = 1088 * 1024;
    wconv_kernel<<<dim3((tot + 255) / 256), dim3(256), 0, stream>>>(MW1, 1088, 1024, MW1tH, MW1tL);
    wconv_kernel<<<dim3((tot + 255) / 256), dim3(256), 0, stream>>>(OW1, 1088, 1024, OW1tH, nullptr);
    tot = 1024 * 1024;
    wconv_kernel<<<dim3((tot + 255) / 256), dim3(256), 0, stream>>>(MW2, 1024, 1024, MW2tH, MW2tL);
    wconv_kernel<<<dim3((tot + 255) / 256), dim3(256), 0, stream>>>(OW2, 1024, 1024, OW2tH, nullptr);
    wconv_kernel<<<dim3((tot + 255) / 256), dim3(256), 0, stream>>>(MW3, 1024, 1024, MW3tH, MW3tL);
    init_summary_kernel<<<dim3(32768), dim3(256), 0, stream>>>(agg, sumH, sacc);
    tow_conv_all_kernel<<<dim3(32768), dim3(256), 0, stream>>>(towers, towAllH);
  }

  const dim3 G(64, 8), B256(256);   // 128x128 tiles over 8192x1024 -> 512 blocks
  for (int k = 0; k < 16; ++k) {
    const _Float16* towH = towAllH + (size_t)k * 8192 * 64;

    // K1m: x=[sum|tow] @ MW1^T -> m1 (2-MFMA: weight-lo kept)
    gemm_split_kernel<<<G, B256, 0, stream>>>(sumH, 1024, towH, 64,
                                              1024, 1088, MW1tH, MW1tL, Mb1, m1H, 1024);
    // K1h: x=[sum|tow] @ OW1^T -> h1 (fp16)
    gemm_h_kernel<<<G, B256, 0, stream>>>(sumH, 1024, towH, 64, 1024, 1088,
                                          OW1tH, Ob1, h1, 1024, nullptr, nullptr);
    // K2m: m1 @ MW2^T -> m2 (2-MFMA)
    gemm_split_kernel<<<G, B256, 0, stream>>>(m1H, 1024, m1H, 1024,
                                              1024, 1024, MW2tH, MW2tL, Mb2, m2H, 1024);
    // K2h: h1 @ OW2^T -> fused relu+dot(OW3) into sacc (fp16)
    gemm_h_kernel<<<G, B256, 0, stream>>>(h1, 1024, h1, 1024, 1024, 1024,
                                          OW2tH, Ob2, nullptr, 1024, OW3, sacc);
    // K3: m2 @ MW3^T -> summary (2-MFMA; in-place: K1m/K1h already consumed it)
    gemm_split_kernel<<<G, B256, 0, stream>>>(m2H, 1024, m2H, 1024,
                                              1024, 1024, MW3tH, MW3tL, Mb3, sumH, 1024);
    // pred + product accumulate + re-zero sacc
    pred_final_kernel<<<dim3(32), B256, 0, stream>>>(sacc, Ob3, out, k);
  }
}

// Round 6
// 2980.261 us; speedup vs baseline: 1.1004x; 1.0326x over previous
//
#include <hip/hip_runtime.h>
#include <cstdint>
#include <cstddef>

// BottomUpNet: N=8192 rows independent; K=16 sequential steps.
// R17 = R16 with launch-config bugfix. R16's failure (absmax 1.3e-5) was
// pred_final_kernel launched with 512 threads while indexing
// blockIdx.x*256+threadIdx.x -> rows 256..8191 each written by TWO blocks
// (race on out/sacc) + OOB rows 8192..16383. GEMM pipeline unchanged:
// audit found no hazard (staged buffer always >=2 barriers from its last
// reader; vmcnt(4) retires exactly tile t+1's loads; lgkm0+sched_barrier
// per rule #18). Structure: 256x128 tiles, G(32,8), 512 thr = 8 waves,
// BK=32, 3 LDS buffers w/ pointer-swap rotation, 2 phases/tile (split) w/
// counted vmcnt + setprio MFMA clusters (T3+T4+T5 combo).
// Per-element MFMA order identical to R13: absmax must be 1.192093e-07.

typedef _Float16 f16x8 __attribute__((ext_vector_type(8)));
typedef float f32x16 __attribute__((ext_vector_type(16)));

#define MF(d, a, b) d = __builtin_amdgcn_mfma_f32_32x32x16_f16(a, b, d, 0, 0, 0)

__device__ __forceinline__ void gload16(const void* g, void* l) {
  // async global->LDS, 16B/lane, LDS dest = wave-uniform base + lane*16
  __builtin_amdgcn_global_load_lds(
      (__attribute__((address_space(1))) void*)const_cast<void*>(g),
      (__attribute__((address_space(3))) void*)l,
      16, 0, 0);
}

// ---- m-GEMM: C = relu(A@B^T + bias); A fp16 hi; B hi/lo fp16 (2 MFMAs).
// Tile 256x128, BK=32, 3-buffer 2-phase pipeline, 512 thr (8 waves).
__global__ __launch_bounds__(512, 2)
void gemm_split_kernel(const _Float16* __restrict__ AH0, int ldA0,
                       const _Float16* __restrict__ AH1, int ldA1,
                       int kcut, int Ktot,
                       const _Float16* __restrict__ BH, const _Float16* __restrict__ BL,
                       const float* __restrict__ bias,
                       _Float16* __restrict__ CH, int ldC)
{
  __shared__ _Float16 sA[3][256 * 32];   // 48 KB
  __shared__ _Float16 sB[3][128 * 32];   // 24 KB
  __shared__ _Float16 sL[3][128 * 32];   // 24 KB

  const int lane = threadIdx.x & 63;
  const int wave = threadIdx.x >> 6;          // 0..7
  const int wm4 = (wave >> 1) * 64;           // 0,64,128,192
  const int wn  = (wave & 1) * 64;            // 0,64
  const int mBase = blockIdx.x * 256, nBase = blockIdx.y * 128;

  // paired-row staging (R13-proven): chunk = 16 logical rows (8 phys 128B rows)
  const int lr  = 2 * (lane >> 3) + ((lane >> 2) & 1);     // logical row 0..15
  const int lcs = (((lane & 3) ^ ((lane >> 3) & 3)) * 8);  // src k-seg (halves)
  const int rA0 = wave * 16 + lr;             // A chunk 'wave'   (rows 0..127)
  const int rA1 = 128 + wave * 16 + lr;       // A chunk 8+wave (rows 128..255)
  const int rB  = wave * 16 + lr;             // B chunk 'wave'   (rows 0..127)

  // fragment reads: row r -> r*32 halves; phys seg = g ^ ((r>>1)&3)
  const int l31 = lane & 31, l5 = lane >> 5;
  const int fswz = (l31 >> 1) & 3;
  const int ko0 = ((l5 ^ fswz) * 8);          // kh=0: g = l5
  const int ko1 = (((2 + l5) ^ fswz) * 8);    // kh=1: g = 2+l5
  const int rA0o = (wm4 + l31) * 32;
  const int rA1o = (wm4 + 32 + l31) * 32;
  const int rB0o = (wn + l31) * 32;
  const int rB1o = (wn + 32 + l31) * 32;

  const _Float16* aP00 = AH0 + (size_t)(mBase + rA0) * ldA0 + lcs;
  const _Float16* aP01 = AH0 + (size_t)(mBase + rA1) * ldA0 + lcs;
  const _Float16* aP10 = AH1 + (size_t)(mBase + rA0) * ldA1 + lcs;
  const _Float16* aP11 = AH1 + (size_t)(mBase + rA1) * ldA1 + lcs;
  const _Float16* bHp  = BH + (size_t)(nBase + rB) * Ktot + lcs;
  const _Float16* bLp  = BL + (size_t)(nBase + rB) * Ktot + lcs;

  f32x16 acc[2][2];
#pragma unroll
  for (int i = 0; i < 2; ++i)
#pragma unroll
    for (int j = 0; j < 2; ++j)
      acc[i][j] = (f32x16)0.0f;

  _Float16 *pA0 = &sA[0][0], *pA1 = &sA[1][0], *pA2 = &sA[2][0];
  _Float16 *pB0 = &sB[0][0], *pB1 = &sB[1][0], *pB2 = &sB[2][0];
  _Float16 *pL0 = &sL[0][0], *pL1 = &sL[1][0], *pL2 = &sL[2][0];

  auto STAGE_A = [&](_Float16* dA, int kt) {     // 2 loads
    const _Float16 *a0, *a1;
    if (kt < kcut) { a0 = aP00 + kt; a1 = aP01 + kt; }
    else           { a0 = aP10 + (kt - kcut); a1 = aP11 + (kt - kcut); }
    gload16(a0, dA + wave * 512);
    gload16(a1, dA + (8 + wave) * 512);
  };
  auto STAGE_B = [&](_Float16* dB, _Float16* dL, int kt) {   // 2 loads
    gload16(bHp + kt, dB + wave * 512);
    gload16(bLp + kt, dL + wave * 512);
  };

  const int NT = Ktot >> 5;                   // 32 or 34
  STAGE_A(pA0, 0);  STAGE_B(pB0, pL0, 0);
  STAGE_A(pA1, 32); STAGE_B(pB1, pL1, 32);
  asm volatile("s_waitcnt vmcnt(4)" ::: "memory");  // tile0's 4 landed
  __builtin_amdgcn_s_barrier();

  for (int t = 0; t < NT; ++t) {
    const int ks = (t + 2) * 32;
    const bool st = (t + 2 < NT);
    // ---------- phase A (j = 0) ----------
    f16x8 a00 = *(const f16x8*)(pA0 + rA0o + ko0);
    f16x8 a01 = *(const f16x8*)(pA0 + rA0o + ko1);
    f16x8 a10 = *(const f16x8*)(pA0 + rA1o + ko0);
    f16x8 a11 = *(const f16x8*)(pA0 + rA1o + ko1);
    f16x8 b00 = *(const f16x8*)(pB0 + rB0o + ko0);
    f16x8 b01 = *(const f16x8*)(pB0 + rB0o + ko1);
    f16x8 c00 = *(const f16x8*)(pL0 + rB0o + ko0);
    f16x8 c01 = *(const f16x8*)(pL0 + rB0o + ko1);
    if (st) STAGE_A(pA2, ks);
    __builtin_amdgcn_s_barrier();
    asm volatile("s_waitcnt lgkmcnt(0)" ::: "memory");
    __builtin_amdgcn_sched_barrier(0);
    __builtin_amdgcn_s_setprio(1);
    MF(acc[0][0], a00, c00); MF(acc[0][0], a00, b00);
    MF(acc[0][0], a01, c01); MF(acc[0][0], a01, b01);
    MF(acc[1][0], a10, c00); MF(acc[1][0], a10, b00);
    MF(acc[1][0], a11, c01); MF(acc[1][0], a11, b01);
    __builtin_amdgcn_s_setprio(0);
    __builtin_amdgcn_s_barrier();
    // ---------- phase B (j = 1) ----------
    f16x8 b10 = *(const f16x8*)(pB0 + rB1o + ko0);
    f16x8 b11 = *(const f16x8*)(pB0 + rB1o + ko1);
    f16x8 c10 = *(const f16x8*)(pL0 + rB1o + ko0);
    f16x8 c11 = *(const f16x8*)(pL0 + rB1o + ko1);
    if (st) {
      STAGE_B(pB2, pL2, ks);
      asm volatile("s_waitcnt vmcnt(4)" ::: "memory");   // t+1's 4 landed
    } else if (t + 1 < NT) {
      asm volatile("s_waitcnt vmcnt(0)" ::: "memory");   // tail drain
    }
    __builtin_amdgcn_s_barrier();
    asm volatile("s_waitcnt lgkmcnt(0)" ::: "memory");
    __builtin_amdgcn_sched_barrier(0);
    __builtin_amdgcn_s_setprio(1);
    MF(acc[0][1], a00, c10); MF(acc[0][1], a00, b10);
    MF(acc[0][1], a01, c11); MF(acc[0][1], a01, b11);
    MF(acc[1][1], a10, c10); MF(acc[1][1], a10, b10);
    MF(acc[1][1], a11, c11); MF(acc[1][1], a11, b11);
    __builtin_amdgcn_s_setprio(0);
    __builtin_amdgcn_s_barrier();
    // rotate buffers (compile-time pointer swap, no modulo)
    _Float16* tp;
    tp = pA0; pA0 = pA1; pA1 = pA2; pA2 = tp;
    tp = pB0; pB0 = pB1; pB1 = pB2; pB2 = tp;
    tp = pL0; pL0 = pL1; pL1 = pL2; pL2 = tp;
  }

  float bv[2];
#pragma unroll
  for (int j = 0; j < 2; ++j) bv[j] = bias[nBase + wn + j * 32 + l31];
#pragma unroll
  for (int i = 0; i < 2; ++i)
#pragma unroll
    for (int j = 0; j < 2; ++j)
#pragma unroll
      for (int r = 0; r < 16; ++r) {
        const int row = mBase + wm4 + i * 32 + (r & 3) + 8 * (r >> 2) + 4 * l5;
        const int col = nBase + wn + j * 32 + l31;
        float v = fmaxf(acc[i][j][r] + bv[j], 0.0f);
        CH[(size_t)row * ldC + col] = (_Float16)v;
      }
}

// ---- fp16 GEMM (hi-only, 1 MFMA): C = relu(A@B^T + bias) fp16 out,
// or fused-pred mode (sacc != null): sacc[row] += sum_col relu(.)*w3[col]
__global__ __launch_bounds__(512, 2)
void gemm_h_kernel(const _Float16* __restrict__ A0, int ldA0,
                   const _Float16* __restrict__ A1, int ldA1,
                   int kcut, int Ktot,
                   const _Float16* __restrict__ B,
                   const float* __restrict__ bias,
                   _Float16* __restrict__ C, int ldC,
                   const float* __restrict__ w3, float* __restrict__ sacc)
{
  __shared__ _Float16 sA[3][256 * 32];
  __shared__ _Float16 sB[3][128 * 32];

  const int lane = threadIdx.x & 63;
  const int wave = threadIdx.x >> 6;
  const int wm4 = (wave >> 1) * 64;
  const int wn  = (wave & 1) * 64;
  const int mBase = blockIdx.x * 256, nBase = blockIdx.y * 128;

  const int lr  = 2 * (lane >> 3) + ((lane >> 2) & 1);
  const int lcs = (((lane & 3) ^ ((lane >> 3) & 3)) * 8);
  const int rA0 = wave * 16 + lr;
  const int rA1 = 128 + wave * 16 + lr;
  const int rB  = wave * 16 + lr;

  const int l31 = lane & 31, l5 = lane >> 5;
  const int fswz = (l31 >> 1) & 3;
  const int ko0 = ((l5 ^ fswz) * 8);
  const int ko1 = (((2 + l5) ^ fswz) * 8);
  const int rA0o = (wm4 + l31) * 32;
  const int rA1o = (wm4 + 32 + l31) * 32;
  const int rB0o = (wn + l31) * 32;
  const int rB1o = (wn + 32 + l31) * 32;

  const _Float16* aP00 = A0 + (size_t)(mBase + rA0) * ldA0 + lcs;
  const _Float16* aP01 = A0 + (size_t)(mBase + rA1) * ldA0 + lcs;
  const _Float16* aP10 = A1 + (size_t)(mBase + rA0) * ldA1 + lcs;
  const _Float16* aP11 = A1 + (size_t)(mBase + rA1) * ldA1 + lcs;
  const _Float16* bHp  = B + (size_t)(nBase + rB) * Ktot + lcs;

  f32x16 acc[2][2];
#pragma unroll
  for (int i = 0; i < 2; ++i)
#pragma unroll
    for (int j = 0; j < 2; ++j)
      acc[i][j] = (f32x16)0.0f;

  _Float16 *pA0 = &sA[0][0], *pA1 = &sA[1][0], *pA2 = &sA[2][0];
  _Float16 *pB0 = &sB[0][0], *pB1 = &sB[1][0], *pB2 = &sB[2][0];

  auto STAGE_A = [&](_Float16* dA, int kt) {     // 2 loads
    const _Float16 *a0, *a1;
    if (kt < kcut) { a0 = aP00 + kt; a1 = aP01 + kt; }
    else           { a0 = aP10 + (kt - kcut); a1 = aP11 + (kt - kcut); }
    gload16(a0, dA + wave * 512);
    gload16(a1, dA + (8 + wave) * 512);
  };
  auto STAGE_B = [&](_Float16* dB, int kt) {     // 1 load
    gload16(bHp + kt, dB + wave * 512);
  };

  const int NT = Ktot >> 5;
  STAGE_A(pA0, 0);  STAGE_B(pB0, 0);
  STAGE_A(pA1, 32); STAGE_B(pB1, 32);
  asm volatile("s_waitcnt vmcnt(3)" ::: "memory");
  __builtin_amdgcn_s_barrier();

  for (int t = 0; t < NT; ++t) {
    const int ks = (t + 2) * 32;
    const bool st = (t + 2 < NT);
    f16x8 a00 = *(const f16x8*)(pA0 + rA0o + ko0);
    f16x8 a01 = *(const f16x8*)(pA0 + rA0o + ko1);
    f16x8 a10 = *(const f16x8*)(pA0 + rA1o + ko0);
    f16x8 a11 = *(const f16x8*)(pA0 + rA1o + ko1);
    f16x8 b00 = *(const f16x8*)(pB0 + rB0o + ko0);
    f16x8 b01 = *(const f16x8*)(pB0 + rB0o + ko1);
    f16x8 b10 = *(const f16x8*)(pB0 + rB1o + ko0);
    f16x8 b11 = *(const f16x8*)(pB0 + rB1o + ko1);
    if (st) {
      STAGE_A(pA2, ks);
      STAGE_B(pB2, ks);
      asm volatile("s_waitcnt vmcnt(3)" ::: "memory");
    } else if (t + 1 < NT) {
      asm volatile("s_waitcnt vmcnt(0)" ::: "memory");
    }
    __builtin_amdgcn_s_barrier();
    asm volatile("s_waitcnt lgkmcnt(0)" ::: "memory");
    __builtin_amdgcn_sched_barrier(0);
    __builtin_amdgcn_s_setprio(1);
    MF(acc[0][0], a00, b00); MF(acc[0][0], a01, b01);
    MF(acc[0][1], a00, b10); MF(acc[0][1], a01, b11);
    MF(acc[1][0], a10, b00); MF(acc[1][0], a11, b01);
    MF(acc[1][1], a10, b10); MF(acc[1][1], a11, b11);
    __builtin_amdgcn_s_setprio(0);
    __builtin_amdgcn_s_barrier();
    _Float16* tp;
    tp = pA0; pA0 = pA1; pA1 = pA2; pA2 = tp;
    tp = pB0; pB0 = pB1; pB1 = pB2; pB2 = tp;
  }

  float bv[2], w3v[2];
#pragma unroll
  for (int j = 0; j < 2; ++j) {
    const int col = nBase + wn + j * 32 + l31;
    bv[j] = bias[col];
    w3v[j] = sacc ? w3[col] : 0.0f;
  }

  if (sacc) {
    // fused pred partial: one value per C/D row, reduced over the 32 col-lanes
#pragma unroll
    for (int i = 0; i < 2; ++i)
#pragma unroll
      for (int r = 0; r < 16; ++r) {
        float pr = 0.0f;
#pragma unroll
        for (int j = 0; j < 2; ++j)
          pr += fmaxf(acc[i][j][r] + bv[j], 0.0f) * w3v[j];
        pr += __shfl_xor(pr, 1);
        pr += __shfl_xor(pr, 2);
        pr += __shfl_xor(pr, 4);
        pr += __shfl_xor(pr, 8);
        pr += __shfl_xor(pr, 16);
        if (l31 == 0)
          atomicAdd(&sacc[mBase + wm4 + i * 32 + (r & 3) + 8 * (r >> 2) + 4 * l5], pr);
      }
  } else {
#pragma unroll
    for (int i = 0; i < 2; ++i)
#pragma unroll
      for (int j = 0; j < 2; ++j)
#pragma unroll
        for (int r = 0; r < 16; ++r) {
          const int row = mBase + wm4 + i * 32 + (r & 3) + 8 * (r >> 2) + 4 * l5;
          const int col = nBase + wn + j * 32 + l31;
          float v = fmaxf(acc[i][j][r] + bv[j], 0.0f);
          C[(size_t)row * ldC + col] = (_Float16)v;
        }
  }
}

// W (K x N fp32, row-major) -> out (N x K fp16 hi[/lo]), i.e. transposed
__global__ void wconv_kernel(const float* __restrict__ W, int K, int N,
                             _Float16* __restrict__ oH, _Float16* __restrict__ oL) {
  int idx = blockIdx.x * 256 + threadIdx.x;   // idx = n*K + k (output-coalesced)
  if (idx >= K * N) return;
  int n = idx / K, k = idx - n * K;
  float v = W[(size_t)k * N + n];
  _Float16 h = (_Float16)v;
  oH[idx] = h;
  if (oL) oL[idx] = (_Float16)(v - (float)h);
}

__global__ void init_summary_kernel(const float* __restrict__ agg,
                                    _Float16* __restrict__ sH,
                                    float* __restrict__ sacc) {
  int idx = blockIdx.x * 256 + threadIdx.x;   // 8192*1024
  sH[idx] = (_Float16)agg[idx & 1023];
  if (idx < 8192) sacc[idx] = 0.0f;
}

// towers [n][k][f] fp32 -> towAll [k][n][f] fp16 hi (all 16 slices)
__global__ void tow_conv_all_kernel(const float* __restrict__ towers,
                                    _Float16* __restrict__ oH) {
  size_t idx = (size_t)blockIdx.x * 256 + threadIdx.x;  // (k*8192+n)*64+f
  int f = idx & 63;
  int n = (int)((idx >> 6) & 8191);
  int k = (int)(idx >> 19);
  oH[idx] = (_Float16)towers[((size_t)n * 16 + k) * 64 + f];
}

// pred = sigmoid(sacc + Ob3); out *= pred; re-zero sacc for next step
__global__ void pred_final_kernel(float* __restrict__ sacc, const float* __restrict__ b3,
                                  float* __restrict__ out, int step) {
  int row = blockIdx.x * 256 + threadIdx.x;   // 8192
  float p = 1.0f / (1.0f + expf(-(sacc[row] + b3[0])));
  out[row] = (step == 0) ? p : out[row] * p;
  sacc[row] = 0.0f;
}

extern "C" void kernel_launch(void* const* d_in, const int* in_sizes, int n_in,
                              void* d_out, int out_size, void* d_ws, size_t ws_size,
                              hipStream_t stream) {
  const float* towers = (const float*)d_in[0];
  const float* agg    = (const float*)d_in[1];
  const float* MW1 = (const float*)d_in[2];
  const float* Mb1 = (const float*)d_in[3];
  const float* MW2 = (const float*)d_in[4];
  const float* Mb2 = (const float*)d_in[5];
  const float* MW3 = (const float*)d_in[6];
  const float* Mb3 = (const float*)d_in[7];
  const float* OW1 = (const float*)d_in[8];
  const float* Ob1 = (const float*)d_in[9];
  const float* OW2 = (const float*)d_in[10];
  const float* Ob2 = (const float*)d_in[11];
  const float* OW3 = (const float*)d_in[12];
  const float* Ob3 = (const float*)d_in[13];
  float* out = (float*)d_out;

  // ws layout (~110 MiB)
  _Float16* p = (_Float16*)d_ws;
  _Float16* MW1tH = p; p += (size_t)1024 * 1088;
  _Float16* MW1tL = p; p += (size_t)1024 * 1088;
  _Float16* OW1tH = p; p += (size_t)1024 * 1088;
  _Float16* MW2tH = p; p += (size_t)1024 * 1024;
  _Float16* MW2tL = p; p += (size_t)1024 * 1024;
  _Float16* OW2tH = p; p += (size_t)1024 * 1024;
  _Float16* MW3tH = p; p += (size_t)1024 * 1024;
  _Float16* MW3tL = p; p += (size_t)1024 * 1024;
  _Float16* sumH  = p; p += (size_t)8192 * 1024;
  _Float16* m1H   = p; p += (size_t)8192 * 1024;
  _Float16* h1    = p; p += (size_t)8192 * 1024;
  _Float16* m2H   = p; p += (size_t)8192 * 1024;
  _Float16* towAllH = p; p += (size_t)16 * 8192 * 64;
  float* sacc = (float*)p;

  // per-call setup: transpose+split weights, convert towers, init summary
  {
    int tot = 1088 * 1024;
    wconv_kernel<<<dim3((tot + 255) / 256), dim3(256), 0, stream>>>(MW1, 1088, 1024, MW1tH, MW1tL);
    wconv_kernel<<<dim3((tot + 255) / 256), dim3(256), 0, stream>>>(OW1, 1088, 1024, OW1tH, nullptr);
    tot = 1024 * 1024;
    wconv_kernel<<<dim3((tot + 255) / 256), dim3(256), 0, stream>>>(MW2, 1024, 1024, MW2tH, MW2tL);
    wconv_kernel<<<dim3((tot + 255) / 256), dim3(256), 0, stream>>>(OW2, 1024, 1024, OW2tH, nullptr);
    wconv_kernel<<<dim3((tot + 255) / 256), dim3(256), 0, stream>>>(MW3, 1024, 1024, MW3tH, MW3tL);
    init_summary_kernel<<<dim3(32768), dim3(256), 0, stream>>>(agg, sumH, sacc);
    tow_conv_all_kernel<<<dim3(32768), dim3(256), 0, stream>>>(towers, towAllH);
  }

  const dim3 G(32, 8), B512(512);   // 256x128 tiles over 8192x1024 -> 256 blocks
  for (int k = 0; k < 16; ++k) {
    const _Float16* towH = towAllH + (size_t)k * 8192 * 64;

    // K1m: x=[sum|tow] @ MW1^T -> m1 (2-MFMA: weight-lo kept)
    gemm_split_kernel<<<G, B512, 0, stream>>>(sumH, 1024, towH, 64,
                                              1024, 1088, MW1tH, MW1tL, Mb1, m1H, 1024);
    // K1h: x=[sum|tow] @ OW1^T -> h1 (fp16)
    gemm_h_kernel<<<G, B512, 0, stream>>>(sumH, 1024, towH, 64, 1024, 1088,
                                          OW1tH, Ob1, h1, 1024, nullptr, nullptr);
    // K2m: m1 @ MW2^T -> m2 (2-MFMA)
    gemm_split_kernel<<<G, B512, 0, stream>>>(m1H, 1024, m1H, 1024,
                                              1024, 1024, MW2tH, MW2tL, Mb2, m2H, 1024);
    // K2h: h1 @ OW2^T -> fused relu+dot(OW3) into sacc (fp16)
    gemm_h_kernel<<<G, B512, 0, stream>>>(h1, 1024, h1, 1024, 1024, 1024,
                                          OW2tH, Ob2, nullptr, 1024, OW3, sacc);
    // K3: m2 @ MW3^T -> summary (2-MFMA; in-place: K1m/K1h already consumed it)
    gemm_split_kernel<<<G, B512, 0, stream>>>(m2H, 1024, m2H, 1024,
                                              1024, 1024, MW3tH, MW3tL, Mb3, sumH, 1024);
    // pred + product accumulate + re-zero sacc
    pred_final_kernel<<<dim3(32), dim3(256), 0, stream>>>(sacc, Ob3, out, k);
  }
}